// Round 1
// baseline (439.306 us; speedup 1.0000x reference)
//
#include <hip/hip_runtime.h>

#define BATCH   1024
#define MSIZE   65536
#define KDIM    256
#define CHOOSEK 128
#define SELK    160        // suffix-count crossing target; actual superset = SELK..SELK+bucket (~350-600)
#define BETA    1e-8f
#define ALPHA   0.5f
// linear u8 key: key = min(255, score*KSCALE). score <= exp(sim-1)*(histmax+beta);
// sims ~ N(0,1/16) => score <~ 6e-4 whp. KSCALE = 256/6e-4. ~385 items/bucket => byte-granular
// threshold yields ncand ~ [160, ~600] << 1024 cap. Monotone quantization keeps superset exact.
#define KSCALE  426666.7f

typedef short bf16x8 __attribute__((ext_vector_type(8)));
typedef float f32x4  __attribute__((ext_vector_type(4)));

__device__ inline unsigned int pack2bf(float a, float b) {   // RNE fp32->bf16 pair
    unsigned int ua = __float_as_uint(a);
    unsigned int ub = __float_as_uint(b);
    ua += 0x7fffu + ((ua >> 16) & 1u);
    ub += 0x7fffu + ((ub >> 16) & 1u);
    return (ua >> 16) | (ub & 0xffff0000u);
}

// async global->LDS, 16B/lane; LDS dest is wave-uniform base + lane*16 (must be linear in tid)
#define GLD16(g, l) __builtin_amdgcn_global_load_lds( \
    (const __attribute__((address_space(1))) unsigned int*)(g), \
    (__attribute__((address_space(3))) unsigned int*)(l), 16, 0, 0)

// -------------------------------------------------------------------------
// Kernel 0: one-time fp32 -> bf16 convert of q and key (removes per-tile VALU
// packing from the GEMM and halves its global read bytes).
// blocks [0,128): q (32768 x 8 floats); blocks [128,8320): key.
// -------------------------------------------------------------------------
__global__ __launch_bounds__(256)
void convert_kernel(const float* __restrict__ q, const float* __restrict__ key,
                    unsigned short* __restrict__ qb, unsigned short* __restrict__ kb)
{
    const int id = blockIdx.x * 256 + threadIdx.x;
    const float* src; unsigned short* dst; int off;
    if (blockIdx.x < 128) { src = q;   dst = qb; off = id; }
    else                  { src = key; dst = kb; off = id - 32768; }
    const float4* s4 = (const float4*)src;
    float4 a = s4[off * 2];
    float4 b = s4[off * 2 + 1];
    uint4 p = make_uint4(pack2bf(a.x, a.y), pack2bf(a.z, a.w),
                         pack2bf(b.x, b.y), pack2bf(b.z, b.w));
    ((uint4*)dst)[off] = p;
}

// -------------------------------------------------------------------------
// Kernel 1: bf16 screening GEMM, m97 structure: 128x128 tile, BK=32, linear LDS,
// global_load_lds width-16 staging, 4 waves x (4x4 of 16x16x32 MFMA).
// Epilogue: u8 key = min(255, exp(sim-1)*(hist+beta)*KSCALE).
// blockIdx mapping: the 8 blocks sharing one key tile get consecutive%8-equal
// bids -> same XCD L2 (key tile fetched once per XCD, reused 8x).
// -------------------------------------------------------------------------
__global__ __launch_bounds__(256)
void score_kernel(const unsigned short* __restrict__ qb,
                  const unsigned short* __restrict__ kb,
                  const float* __restrict__ hist,
                  unsigned char* __restrict__ s8)
{
    __shared__ __align__(16) unsigned short As[128 * 32];
    __shared__ __align__(16) unsigned short Bs[128 * 32];
    const int tid = threadIdx.x;
    const int bid = blockIdx.x;
    const int b0 = ((bid >> 3) & 7) * 128;                 // batch tile (8)
    const int n0 = ((bid & 7) + ((bid >> 6) << 3)) * 128;  // memory tile (512), XCD-grouped
    const int lane = tid & 63, wave = tid >> 6;
    const int wm = (wave >> 1) * 64, wn = (wave & 1) * 64;
    const int l15 = lane & 15, l4 = lane >> 4;

    f32x4 acc[4][4] = {};

    const int srow = tid >> 2;          // staging row 0..63 (per half)
    const int seg  = (tid & 3) * 8;     // 8-element column segment
    const unsigned short* gA = qb + (size_t)(b0 + srow) * KDIM + seg;
    const unsigned short* gB = kb + (size_t)(n0 + srow) * KDIM + seg;
    unsigned short* lA = As + srow * 32 + seg;   // byte offset = tid*16, linear per wave
    unsigned short* lB = Bs + srow * 32 + seg;

    for (int ks = 0; ks < KDIM; ks += 32) {
        GLD16(gA + ks,             lA);
        GLD16(gA + ks + 64 * KDIM, lA + 64 * 32);
        GLD16(gB + ks,             lB);
        GLD16(gB + ks + 64 * KDIM, lB + 64 * 32);
        __syncthreads();                 // backend drains vmcnt(0) before s_barrier

        bf16x8 af[4], bfr[4];
#pragma unroll
        for (int i = 0; i < 4; ++i)
            af[i] = *(const bf16x8*)(As + (wm + i * 16 + l15) * 32 + l4 * 8);
#pragma unroll
        for (int j = 0; j < 4; ++j)
            bfr[j] = *(const bf16x8*)(Bs + (wn + j * 16 + l15) * 32 + l4 * 8);
#pragma unroll
        for (int i = 0; i < 4; ++i)
#pragma unroll
            for (int j = 0; j < 4; ++j)
                acc[i][j] = __builtin_amdgcn_mfma_f32_16x16x32_bf16(af[i], bfr[j], acc[i][j], 0, 0, 0);
        __syncthreads();
    }

    // epilogue: C/D layout col = lane&15, row = (lane>>4)*4 + reg (verified prev session)
    float hj[4];
#pragma unroll
    for (int j = 0; j < 4; ++j)
        hj[j] = (hist[n0 + wn + j * 16 + l15] + BETA) * KSCALE;
#pragma unroll
    for (int i = 0; i < 4; ++i) {
        const size_t rbase = (size_t)(b0 + wm + i * 16 + l4 * 4) * MSIZE;
#pragma unroll
        for (int j = 0; j < 4; ++j) {
            const int n = n0 + wn + j * 16 + l15;
#pragma unroll
            for (int reg = 0; reg < 4; ++reg) {
                float sc = __expf(acc[i][j][reg] - 1.0f) * hj[j];
                s8[rbase + (size_t)reg * MSIZE + n] = (unsigned char)(int)fminf(sc, 255.0f);
            }
        }
    }
}

// -------------------------------------------------------------------------
// Kernel 2: per batch row. ONE global pass: whole 64KB u8 row -> 16 uint4 regs.
// One 256-bucket histogram (byte buckets), suffix scan -> H (crossing SELK),
// in-register collect of bytes >= H (superset of exact top-128), exact fp32
// rescore, count-based exact top-128 (ties -> lower index), weighted sum.
// LDS ~34.9KB -> 4 blocks/CU.
// -------------------------------------------------------------------------
__global__ __launch_bounds__(256, 4)
void select_kernel(const float* __restrict__ q,
                   const float* __restrict__ key,
                   const float* __restrict__ hist,
                   const float* __restrict__ vals,
                   const unsigned char* __restrict__ s8,
                   float* __restrict__ out)
{
    const int b   = blockIdx.x;
    const int tid = threadIdx.x;

    __shared__ __align__(16) float qs[KDIM];
    __shared__ unsigned int hcnt[16 * 257];   // 16 replicated histograms
    __shared__ int   stot[256];
    __shared__ int   scal[2];                 // 0:H  1:ncand
    __shared__ int   cidx[1024];
    __shared__ float csc[1024], cjj[1024], cjv[1024];
    __shared__ float wred[8];

    qs[tid] = q[(size_t)b * KDIM + tid];
    for (int i = tid; i < 16 * 257; i += 256) hcnt[i] = 0u;
    if (tid == 0) scal[1] = 0;
    __syncthreads();

    const uint4* rowp = reinterpret_cast<const uint4*>(s8 + (size_t)b * MSIZE);
    const int rep = (tid & 15) * 257;

    // ---- single global read: whole row into registers ----
    uint4 vv[16];
#pragma unroll
    for (int i = 0; i < 16; ++i) vv[i] = rowp[i * 256 + tid];

    // ---- histogram of byte keys ----
#pragma unroll
    for (int i = 0; i < 16; ++i) {
        unsigned int w[4] = {vv[i].x, vv[i].y, vv[i].z, vv[i].w};
#pragma unroll
        for (int k = 0; k < 4; ++k) {
            atomicAdd(&hcnt[rep + (w[k] & 0xffu)], 1u);
            atomicAdd(&hcnt[rep + ((w[k] >> 8) & 0xffu)], 1u);
            atomicAdd(&hcnt[rep + ((w[k] >> 16) & 0xffu)], 1u);
            atomicAdd(&hcnt[rep + (w[k] >> 24)], 1u);
        }
    }
    __syncthreads();
    { unsigned int t = 0;
#pragma unroll
      for (int k = 0; k < 16; ++k) t += hcnt[k * 257 + tid];
      stot[tid] = (int)t; }
    __syncthreads();
    for (int off = 1; off < 256; off <<= 1) {   // suffix sum
        int v = stot[tid] + ((tid + off < 256) ? stot[tid + off] : 0);
        __syncthreads(); stot[tid] = v; __syncthreads();
    }
    { int sH = stot[tid], sN = (tid < 255) ? stot[tid + 1] : 0;
      if (sH >= SELK && sN < SELK) scal[0] = tid; }
    __syncthreads();
    const unsigned int H = (unsigned int)scal[0];

    // ---- collect candidates (byte >= H) from registers — no global re-read ----
#pragma unroll
    for (int i = 0; i < 16; ++i) {
        const int base = (i * 256 + tid) * 16;
        unsigned int w[4] = {vv[i].x, vv[i].y, vv[i].z, vv[i].w};
#pragma unroll
        for (int k = 0; k < 4; ++k) {
#pragma unroll
            for (int jj = 0; jj < 4; ++jj) {
                unsigned int bb = (w[k] >> (8 * jj)) & 0xffu;
                if (bb >= H) {
                    int p = atomicAdd(&scal[1], 1);
                    if (p < 1024) cidx[p] = base + 4 * k + jj;
                }
            }
        }
    }
    __syncthreads();
    const int ncand = min(scal[1], 1024);

    // ---- exact fp32 rescore of candidates ----
    const int wave = tid >> 6, lane = tid & 63;
    for (int i = wave; i < ncand; i += 4) {
        const int idx = cidx[i];
        float4 kk = *reinterpret_cast<const float4*>(&key[(size_t)idx * KDIM + lane * 4]);
        float4 qq = *reinterpret_cast<const float4*>(&qs[lane * 4]);
        float p = kk.x * qq.x + kk.y * qq.y + kk.z * qq.z + kk.w * qq.w;
#pragma unroll
        for (int off = 32; off > 0; off >>= 1) p += __shfl_xor(p, off, 64);
        if (lane == 0) {
            float e = expf(p - 1.0f);
            float h = hist[idx];
            csc[i] = e * (h + BETA);
            float j = e * (ALPHA * h + BETA);
            cjj[i] = j;
            cjv[i] = j * vals[idx];
        }
    }
    __syncthreads();

    // ---- exact top-128 among candidates (count-based; ties -> lower index) ----
    float pn = 0.f, pd = 0.f;
    for (int i = tid; i < ncand; i += 256) {
        float si = csc[i]; int ii = cidx[i]; int rank = 0;
        for (int t = 0; t < ncand; ++t) {
            float st = csc[t];
            rank += (st > si || (st == si && cidx[t] < ii)) ? 1 : 0;
        }
        if (rank < CHOOSEK) { pn += cjv[i]; pd += cjj[i]; }
    }
#pragma unroll
    for (int off = 32; off > 0; off >>= 1) {
        pn += __shfl_xor(pn, off, 64);
        pd += __shfl_xor(pd, off, 64);
    }
    if (lane == 0) { wred[wave] = pn; wred[4 + wave] = pd; }
    __syncthreads();
    if (tid == 0) {
        float n = wred[0] + wred[1] + wred[2] + wred[3];
        float d = wred[4] + wred[5] + wred[6] + wred[7];
        out[b] = n / d;
    }
}

// -------------------------------------------------------------------------
extern "C" void kernel_launch(void* const* d_in, const int* in_sizes, int n_in,
                              void* d_out, int out_size, void* d_ws, size_t ws_size,
                              hipStream_t stream)
{
    (void)in_sizes; (void)n_in; (void)out_size; (void)ws_size;
    const float* q    = (const float*)d_in[0];
    const float* key  = (const float*)d_in[1];
    const float* hist = (const float*)d_in[2];
    const float* vals = (const float*)d_in[3];
    float* out = (float*)d_out;

    // workspace layout (96.5 MiB total, < previous 128 MiB):
    unsigned char*  s8 = (unsigned char*)d_ws;                                  // 64 MiB u8 keys
    unsigned short* kb = (unsigned short*)((char*)d_ws + ((size_t)64 << 20));   // 32 MiB bf16 key
    unsigned short* qb = (unsigned short*)((char*)d_ws + ((size_t)96 << 20));   // 512 KiB bf16 q

    convert_kernel<<<8320, 256, 0, stream>>>(q, key, qb, kb);
    score_kernel<<<4096, 256, 0, stream>>>(qb, kb, hist, s8);
    select_kernel<<<BATCH, 256, 0, stream>>>(q, key, hist, vals, s8, out);
}

// Round 2
// 230.818 us; speedup vs baseline: 1.9033x; 1.9033x over previous
//
#include <hip/hip_runtime.h>

#define BATCH   1024
#define MSIZE   65536
#define KDIM    256
#define CHOOSEK 128
#define SELK    160        // suffix-count crossing target; superset = SELK..SELK+bucket (~350-600)
#define BETA    1e-8f
#define ALPHA   0.5f
// linear u8 key: key = min(255, score*KSCALE). score <= exp(sim-1)*(histmax+beta);
// sims ~ N(0,1/16) => score <~ 6e-4 whp. KSCALE = 256/6e-4. ~330 items/bucket => byte-granular
// threshold yields ncand ~ [160, ~700] << 1024 cap. Monotone quantization keeps superset exact.
#define KSCALE  426666.7f

typedef short bf16x8 __attribute__((ext_vector_type(8)));
typedef float f32x4  __attribute__((ext_vector_type(4)));

__device__ inline unsigned int pack2bf(float a, float b) {   // RNE fp32->bf16 pair
    unsigned int ua = __float_as_uint(a);
    unsigned int ub = __float_as_uint(b);
    ua += 0x7fffu + ((ua >> 16) & 1u);
    ub += 0x7fffu + ((ub >> 16) & 1u);
    return (ua >> 16) | (ub & 0xffff0000u);
}

// async global->LDS, 16B/lane; LDS dest is wave-uniform base + lane*16 (must be linear in tid)
#define GLD16(g, l) __builtin_amdgcn_global_load_lds( \
    (const __attribute__((address_space(1))) unsigned int*)(g), \
    (__attribute__((address_space(3))) unsigned int*)(l), 16, 0, 0)

// -------------------------------------------------------------------------
// Kernel 0: one-time fp32 -> bf16 convert of q and key.
// -------------------------------------------------------------------------
__global__ __launch_bounds__(256)
void convert_kernel(const float* __restrict__ q, const float* __restrict__ key,
                    unsigned short* __restrict__ qb, unsigned short* __restrict__ kb)
{
    const int id = blockIdx.x * 256 + threadIdx.x;
    const float* src; unsigned short* dst; int off;
    if (blockIdx.x < 128) { src = q;   dst = qb; off = id; }
    else                  { src = key; dst = kb; off = id - 32768; }
    const float4* s4 = (const float4*)src;
    float4 a = s4[off * 2];
    float4 b = s4[off * 2 + 1];
    uint4 p = make_uint4(pack2bf(a.x, a.y), pack2bf(a.z, a.w),
                         pack2bf(b.x, b.y), pack2bf(b.z, b.w));
    ((uint4*)dst)[off] = p;
}

// -------------------------------------------------------------------------
// Kernel 1: bf16 screening GEMM, m97 structure: 128x128 tile, BK=32, linear LDS,
// global_load_lds width-16 staging, 4 waves x (4x4 of 16x16x32 MFMA).
// Epilogue: u8 key = min(255, exp(sim-1)*(hist+beta)*KSCALE).
// -------------------------------------------------------------------------
__global__ __launch_bounds__(256)
void score_kernel(const unsigned short* __restrict__ qb,
                  const unsigned short* __restrict__ kb,
                  const float* __restrict__ hist,
                  unsigned char* __restrict__ s8)
{
    __shared__ __align__(16) unsigned short As[128 * 32];
    __shared__ __align__(16) unsigned short Bs[128 * 32];
    const int tid = threadIdx.x;
    const int bid = blockIdx.x;
    const int b0 = ((bid >> 3) & 7) * 128;                 // batch tile (8)
    const int n0 = ((bid & 7) + ((bid >> 6) << 3)) * 128;  // memory tile (512), XCD-grouped
    const int lane = tid & 63, wave = tid >> 6;
    const int wm = (wave >> 1) * 64, wn = (wave & 1) * 64;
    const int l15 = lane & 15, l4 = lane >> 4;

    f32x4 acc[4][4] = {};

    const int srow = tid >> 2;          // staging row 0..63 (per half)
    const int seg  = (tid & 3) * 8;     // 8-element column segment
    const unsigned short* gA = qb + (size_t)(b0 + srow) * KDIM + seg;
    const unsigned short* gB = kb + (size_t)(n0 + srow) * KDIM + seg;
    unsigned short* lA = As + srow * 32 + seg;   // byte offset = tid*16, linear per wave
    unsigned short* lB = Bs + srow * 32 + seg;

    for (int ks = 0; ks < KDIM; ks += 32) {
        GLD16(gA + ks,             lA);
        GLD16(gA + ks + 64 * KDIM, lA + 64 * 32);
        GLD16(gB + ks,             lB);
        GLD16(gB + ks + 64 * KDIM, lB + 64 * 32);
        __syncthreads();                 // backend drains vmcnt(0) before s_barrier

        bf16x8 af[4], bfr[4];
#pragma unroll
        for (int i = 0; i < 4; ++i)
            af[i] = *(const bf16x8*)(As + (wm + i * 16 + l15) * 32 + l4 * 8);
#pragma unroll
        for (int j = 0; j < 4; ++j)
            bfr[j] = *(const bf16x8*)(Bs + (wn + j * 16 + l15) * 32 + l4 * 8);
#pragma unroll
        for (int i = 0; i < 4; ++i)
#pragma unroll
            for (int j = 0; j < 4; ++j)
                acc[i][j] = __builtin_amdgcn_mfma_f32_16x16x32_bf16(af[i], bfr[j], acc[i][j], 0, 0, 0);
        __syncthreads();
    }

    // epilogue: C/D layout col = lane&15, row = (lane>>4)*4 + reg (verified prev session)
    float hj[4];
#pragma unroll
    for (int j = 0; j < 4; ++j)
        hj[j] = (hist[n0 + wn + j * 16 + l15] + BETA) * KSCALE;
#pragma unroll
    for (int i = 0; i < 4; ++i) {
        const size_t rbase = (size_t)(b0 + wm + i * 16 + l4 * 4) * MSIZE;
#pragma unroll
        for (int j = 0; j < 4; ++j) {
            const int n = n0 + wn + j * 16 + l15;
#pragma unroll
            for (int reg = 0; reg < 4; ++reg) {
                float sc = __expf(acc[i][j][reg] - 1.0f) * hj[j];
                s8[rbase + (size_t)reg * MSIZE + n] = (unsigned char)(int)fminf(sc, 255.0f);
            }
        }
    }
}

// -------------------------------------------------------------------------
// Kernel 2: per batch row. Streaming two-pass (row is L3-resident, re-read is
// cheap; NO register-held row -> no scratch spill):
//   pass 1: byte histogram (16 replicated LDS histograms)
//   suffix scan -> threshold byte H (crossing SELK)
//   pass 2: collect candidates (byte >= H), superset of exact top-128
//   exact fp32 rescore + count-based exact top-128 + weighted sum.
// LDS ~34.9KB -> 4 blocks/CU.
// -------------------------------------------------------------------------
__global__ __launch_bounds__(256, 4)
void select_kernel(const float* __restrict__ q,
                   const float* __restrict__ key,
                   const float* __restrict__ hist,
                   const float* __restrict__ vals,
                   const unsigned char* __restrict__ s8,
                   float* __restrict__ out)
{
    const int b   = blockIdx.x;
    const int tid = threadIdx.x;

    __shared__ __align__(16) float qs[KDIM];
    __shared__ unsigned int hcnt[16 * 257];   // 16 replicated histograms
    __shared__ int   stot[256];
    __shared__ int   scal[2];                 // 0:H  1:ncand
    __shared__ int   cidx[1024];
    __shared__ float csc[1024], cjj[1024], cjv[1024];
    __shared__ float wred[8];

    qs[tid] = q[(size_t)b * KDIM + tid];
    for (int i = tid; i < 16 * 257; i += 256) hcnt[i] = 0u;
    if (tid == 0) scal[1] = 0;
    __syncthreads();

    const uint4* rowp = reinterpret_cast<const uint4*>(s8 + (size_t)b * MSIZE);
    const int rep = (tid & 15) * 257;

    // ---- pass 1: byte histogram (stream, nothing held) ----
    for (int i = 0; i < 16; ++i) {
        uint4 v = rowp[i * 256 + tid];
        unsigned int w[4] = {v.x, v.y, v.z, v.w};
#pragma unroll
        for (int k = 0; k < 4; ++k) {
            atomicAdd(&hcnt[rep + (w[k] & 0xffu)], 1u);
            atomicAdd(&hcnt[rep + ((w[k] >> 8) & 0xffu)], 1u);
            atomicAdd(&hcnt[rep + ((w[k] >> 16) & 0xffu)], 1u);
            atomicAdd(&hcnt[rep + (w[k] >> 24)], 1u);
        }
    }
    __syncthreads();
    { unsigned int t = 0;
#pragma unroll
      for (int k = 0; k < 16; ++k) t += hcnt[k * 257 + tid];
      stot[tid] = (int)t; }
    __syncthreads();
    for (int off = 1; off < 256; off <<= 1) {   // suffix sum
        int v = stot[tid] + ((tid + off < 256) ? stot[tid + off] : 0);
        __syncthreads(); stot[tid] = v; __syncthreads();
    }
    { int sH = stot[tid], sN = (tid < 255) ? stot[tid + 1] : 0;
      if (sH >= SELK && sN < SELK) scal[0] = tid; }
    __syncthreads();
    const unsigned int H = (unsigned int)scal[0];

    // ---- pass 2: collect candidates (byte >= H); row re-read hits L3 ----
    for (int i = 0; i < 16; ++i) {
        uint4 v = rowp[i * 256 + tid];
        const int base = (i * 256 + tid) * 16;
        unsigned int w[4] = {v.x, v.y, v.z, v.w};
#pragma unroll
        for (int k = 0; k < 4; ++k) {
#pragma unroll
            for (int jj = 0; jj < 4; ++jj) {
                unsigned int bb = (w[k] >> (8 * jj)) & 0xffu;
                if (bb >= H) {
                    int p = atomicAdd(&scal[1], 1);
                    if (p < 1024) cidx[p] = base + 4 * k + jj;
                }
            }
        }
    }
    __syncthreads();
    const int ncand = min(scal[1], 1024);

    // ---- exact fp32 rescore of candidates ----
    const int wave = tid >> 6, lane = tid & 63;
    for (int i = wave; i < ncand; i += 4) {
        const int idx = cidx[i];
        float4 kk = *reinterpret_cast<const float4*>(&key[(size_t)idx * KDIM + lane * 4]);
        float4 qq = *reinterpret_cast<const float4*>(&qs[lane * 4]);
        float p = kk.x * qq.x + kk.y * qq.y + kk.z * qq.z + kk.w * qq.w;
#pragma unroll
        for (int off = 32; off > 0; off >>= 1) p += __shfl_xor(p, off, 64);
        if (lane == 0) {
            float e = expf(p - 1.0f);
            float h = hist[idx];
            csc[i] = e * (h + BETA);
            float j = e * (ALPHA * h + BETA);
            cjj[i] = j;
            cjv[i] = j * vals[idx];
        }
    }
    __syncthreads();

    // ---- exact top-128 among candidates (count-based; ties -> lower index) ----
    float pn = 0.f, pd = 0.f;
    for (int i = tid; i < ncand; i += 256) {
        float si = csc[i]; int ii = cidx[i]; int rank = 0;
        for (int t = 0; t < ncand; ++t) {
            float st = csc[t];
            rank += (st > si || (st == si && cidx[t] < ii)) ? 1 : 0;
        }
        if (rank < CHOOSEK) { pn += cjv[i]; pd += cjj[i]; }
    }
#pragma unroll
    for (int off = 32; off > 0; off >>= 1) {
        pn += __shfl_xor(pn, off, 64);
        pd += __shfl_xor(pd, off, 64);
    }
    if (lane == 0) { wred[wave] = pn; wred[4 + wave] = pd; }
    __syncthreads();
    if (tid == 0) {
        float n = wred[0] + wred[1] + wred[2] + wred[3];
        float d = wred[4] + wred[5] + wred[6] + wred[7];
        out[b] = n / d;
    }
}

// -------------------------------------------------------------------------
extern "C" void kernel_launch(void* const* d_in, const int* in_sizes, int n_in,
                              void* d_out, int out_size, void* d_ws, size_t ws_size,
                              hipStream_t stream)
{
    (void)in_sizes; (void)n_in; (void)out_size; (void)ws_size;
    const float* q    = (const float*)d_in[0];
    const float* key  = (const float*)d_in[1];
    const float* hist = (const float*)d_in[2];
    const float* vals = (const float*)d_in[3];
    float* out = (float*)d_out;

    // workspace layout (96.5 MiB total):
    unsigned char*  s8 = (unsigned char*)d_ws;                                  // 64 MiB u8 keys
    unsigned short* kb = (unsigned short*)((char*)d_ws + ((size_t)64 << 20));   // 32 MiB bf16 key
    unsigned short* qb = (unsigned short*)((char*)d_ws + ((size_t)96 << 20));   // 512 KiB bf16 q

    convert_kernel<<<8320, 256, 0, stream>>>(q, key, qb, kb);
    score_kernel<<<4096, 256, 0, stream>>>(qb, kb, hist, s8);
    select_kernel<<<BATCH, 256, 0, stream>>>(q, key, hist, vals, s8, out);
}

// Round 3
// 210.690 us; speedup vs baseline: 2.0851x; 1.0955x over previous
//
#include <hip/hip_runtime.h>

#define BATCH   1024
#define MSIZE   65536
#define KDIM    256
#define CHOOSEK 128
#define SELK    160        // suffix-count crossing target; superset = SELK..SELK+bucket (~350-600)
#define BETA    1e-8f
#define ALPHA   0.5f
// linear u8 key: key = min(255, score*KSCALE). score <= exp(sim-1)*(histmax+beta);
// sims ~ N(0,1/16) => score <~ 6e-4 whp. KSCALE = 256/6e-4. ~330 items/bucket => byte-granular
// threshold yields ncand ~ [160, ~700] << 1024 cap. Monotone quantization keeps superset exact.
#define KSCALE  426666.7f

typedef short bf16x8 __attribute__((ext_vector_type(8)));
typedef float f32x4  __attribute__((ext_vector_type(4)));

__device__ inline unsigned int pack2bf(float a, float b) {   // RNE fp32->bf16 pair
    unsigned int ua = __float_as_uint(a);
    unsigned int ub = __float_as_uint(b);
    ua += 0x7fffu + ((ua >> 16) & 1u);
    ub += 0x7fffu + ((ub >> 16) & 1u);
    return (ua >> 16) | (ub & 0xffff0000u);
}

// async global->LDS, 16B/lane; LDS dest is wave-uniform base + lane*16 (must be linear in tid)
#define GLD16(g, l) __builtin_amdgcn_global_load_lds( \
    (const __attribute__((address_space(1))) unsigned int*)(g), \
    (__attribute__((address_space(3))) unsigned int*)(l), 16, 0, 0)

// -------------------------------------------------------------------------
// Kernel 0: one-time fp32 -> bf16 convert of q and key.
// -------------------------------------------------------------------------
__global__ __launch_bounds__(256)
void convert_kernel(const float* __restrict__ q, const float* __restrict__ key,
                    unsigned short* __restrict__ qb, unsigned short* __restrict__ kb)
{
    const int id = blockIdx.x * 256 + threadIdx.x;
    const float* src; unsigned short* dst; int off;
    if (blockIdx.x < 128) { src = q;   dst = qb; off = id; }
    else                  { src = key; dst = kb; off = id - 32768; }
    const float4* s4 = (const float4*)src;
    float4 a = s4[off * 2];
    float4 b = s4[off * 2 + 1];
    uint4 p = make_uint4(pack2bf(a.x, a.y), pack2bf(a.z, a.w),
                         pack2bf(b.x, b.y), pack2bf(b.z, b.w));
    ((uint4*)dst)[off] = p;
}

// -------------------------------------------------------------------------
// Kernel 1: bf16 screening GEMM, 128x128 tile, BK=32, DOUBLE-BUFFERED LDS
// (T3 minimum 2-phase: issue next tile's global_load_lds BEFORE computing the
// current tile; single barrier per step drains vmcnt+lgkmcnt).
// Epilogue: u8 key = min(255, exp(sim-1)*(hist+beta)*KSCALE).
// -------------------------------------------------------------------------
__global__ __launch_bounds__(256)
void score_kernel(const unsigned short* __restrict__ qb,
                  const unsigned short* __restrict__ kb,
                  const float* __restrict__ hist,
                  unsigned char* __restrict__ s8)
{
    __shared__ __align__(16) unsigned short As[2][128 * 32];
    __shared__ __align__(16) unsigned short Bs[2][128 * 32];
    const int tid = threadIdx.x;
    const int bid = blockIdx.x;
    const int b0 = ((bid >> 3) & 7) * 128;                 // batch tile (8)
    const int n0 = ((bid & 7) + ((bid >> 6) << 3)) * 128;  // memory tile (512), XCD-grouped
    const int lane = tid & 63, wave = tid >> 6;
    const int wm = (wave >> 1) * 64, wn = (wave & 1) * 64;
    const int l15 = lane & 15, l4 = lane >> 4;

    f32x4 acc[4][4] = {};

    const int srow = tid >> 2;          // staging row 0..63 (per half)
    const int seg  = (tid & 3) * 8;     // 8-element column segment
    const unsigned short* gA = qb + (size_t)(b0 + srow) * KDIM + seg;
    const unsigned short* gB = kb + (size_t)(n0 + srow) * KDIM + seg;
    const int lofs = srow * 32 + seg;   // element offset; byte offset = tid*16 (linear)

    // prologue: stage K-step 0 into buffer 0
    GLD16(gA,             &As[0][lofs]);
    GLD16(gA + 64 * KDIM, &As[0][lofs + 64 * 32]);
    GLD16(gB,             &Bs[0][lofs]);
    GLD16(gB + 64 * KDIM, &Bs[0][lofs + 64 * 32]);
    __syncthreads();                    // vmcnt(0) drained -> buf0 ready

#pragma unroll
    for (int ks = 0; ks < 8; ++ks) {
        const int cur = ks & 1;
        if (ks < 7) {                   // issue next-tile loads FIRST (overlap with MFMA below)
            const int nxt = cur ^ 1;
            const int ko  = (ks + 1) * 32;
            GLD16(gA + ko,             &As[nxt][lofs]);
            GLD16(gA + ko + 64 * KDIM, &As[nxt][lofs + 64 * 32]);
            GLD16(gB + ko,             &Bs[nxt][lofs]);
            GLD16(gB + ko + 64 * KDIM, &Bs[nxt][lofs + 64 * 32]);
        }
        bf16x8 af[4], bfr[4];
#pragma unroll
        for (int i = 0; i < 4; ++i)
            af[i] = *(const bf16x8*)(&As[cur][(wm + i * 16 + l15) * 32 + l4 * 8]);
#pragma unroll
        for (int j = 0; j < 4; ++j)
            bfr[j] = *(const bf16x8*)(&Bs[cur][(wn + j * 16 + l15) * 32 + l4 * 8]);
#pragma unroll
        for (int i = 0; i < 4; ++i)
#pragma unroll
            for (int j = 0; j < 4; ++j)
                acc[i][j] = __builtin_amdgcn_mfma_f32_16x16x32_bf16(af[i], bfr[j], acc[i][j], 0, 0, 0);
        __syncthreads();                // drains vmcnt (next buf ready) + lgkmcnt (reads done)
    }

    // epilogue: C/D layout col = lane&15, row = (lane>>4)*4 + reg (verified prev session)
    float hj[4];
#pragma unroll
    for (int j = 0; j < 4; ++j)
        hj[j] = (hist[n0 + wn + j * 16 + l15] + BETA) * KSCALE;
#pragma unroll
    for (int i = 0; i < 4; ++i) {
        const size_t rbase = (size_t)(b0 + wm + i * 16 + l4 * 4) * MSIZE;
#pragma unroll
        for (int j = 0; j < 4; ++j) {
            const int n = n0 + wn + j * 16 + l15;
#pragma unroll
            for (int reg = 0; reg < 4; ++reg) {
                float sc = __expf(acc[i][j][reg] - 1.0f) * hj[j];
                s8[rbase + (size_t)reg * MSIZE + n] = (unsigned char)(int)fminf(sc, 255.0f);
            }
        }
    }
}

// -------------------------------------------------------------------------
// Kernel 2: per batch row, latency-optimized (grid is 4 blocks/CU -> serial
// speed of one block is what matters):
//   pass 1: histogram ONLY bytes >= 128 (word prescreen w&0x80808080), since
//           threshold ~190-210. Exact fallback (full histogram) if suffix
//           count at 128 < SELK. ~40x fewer LDS atomics.
//   scan:   single-wave shfl suffix-scan (replaces 16-barrier log-scan).
//   pass 2: collect bytes >= H with same bit7 word prescreen (H>=128 path).
//   rescore: 16-lane groups -> 4 dots/wave in flight, 4-hop reduce.
//   exact count-based top-128 (ties -> lower index) + weighted sum.
// -------------------------------------------------------------------------
__global__ __launch_bounds__(256, 4)
void select_kernel(const float* __restrict__ q,
                   const float* __restrict__ key,
                   const float* __restrict__ hist,
                   const float* __restrict__ vals,
                   const unsigned char* __restrict__ s8,
                   float* __restrict__ out)
{
    const int b   = blockIdx.x;
    const int tid = threadIdx.x;

    __shared__ __align__(16) float qs[KDIM];
    __shared__ unsigned int hcnt[16 * 257];   // 16 replicated histograms
    __shared__ int   stot[256];
    __shared__ int   scal[2];                 // 0:H  1:ncand
    __shared__ int   cidx[1024];
    __shared__ float csc[1024], cjj[1024], cjv[1024];
    __shared__ float wred[8];

    qs[tid] = q[(size_t)b * KDIM + tid];
    const uint4* rowp = reinterpret_cast<const uint4*>(s8 + (size_t)b * MSIZE);
    const int rep = (tid & 15) * 257;

    // ---- threshold search: prescreened histogram, exact fallback ----
    int H = -1;
    int minb = 128;
    for (;;) {
        for (int i = tid; i < 16 * 257; i += 256) hcnt[i] = 0u;
        if (tid == 0) { scal[0] = -1; scal[1] = 0; }
        __syncthreads();

        for (int i = 0; i < 16; ++i) {
            uint4 v = rowp[i * 256 + tid];
            unsigned int w[4] = {v.x, v.y, v.z, v.w};
#pragma unroll
            for (int k = 0; k < 4; ++k) {
                if (minb == 0 || (w[k] & 0x80808080u)) {
#pragma unroll
                    for (int jj = 0; jj < 4; ++jj) {
                        int bb = (int)((w[k] >> (8 * jj)) & 0xffu);
                        if (bb >= minb) atomicAdd(&hcnt[rep + bb], 1u);
                    }
                }
            }
        }
        __syncthreads();
        { unsigned int t = 0;
#pragma unroll
          for (int k = 0; k < 16; ++k) t += hcnt[k * 257 + tid];
          stot[tid] = (int)t; }
        __syncthreads();

        // single-wave suffix scan over 256 bins; find crossing S[b]>=SELK>S[b+1]
        if (tid < 64) {
            const int l = tid;
            int t0 = stot[l * 4], t1 = stot[l * 4 + 1], t2 = stot[l * 4 + 2], t3 = stot[l * 4 + 3];
            int lsum = t0 + t1 + t2 + t3;
            int s = lsum;
#pragma unroll
            for (int off = 1; off < 64; off <<= 1) {
                int u = __shfl_down(s, off, 64);
                if (l + off < 64) s += u;
            }
            int A  = s - lsum;        // sum over lanes > l (== S[4l+4])
            int S3 = A + t3;
            int S2 = S3 + t2;
            int S1 = S2 + t1;
            int S0 = S1 + t0;
            if (S0 >= SELK && S1 < SELK) scal[0] = l * 4 + 0;
            if (S1 >= SELK && S2 < SELK) scal[0] = l * 4 + 1;
            if (S2 >= SELK && S3 < SELK) scal[0] = l * 4 + 2;
            if (S3 >= SELK && A  < SELK) scal[0] = l * 4 + 3;
        }
        __syncthreads();
        H = scal[0];
        __syncthreads();              // all threads read H before next-iter rewrites
        if (H >= 0) break;
        minb = 0;                     // threshold below 128: exact full histogram
    }

    // ---- pass 2: collect candidates (byte >= H); row re-read hits L3 ----
    const unsigned int uH = (unsigned int)H;
    const bool pre = (H >= 128);
    for (int i = 0; i < 16; ++i) {
        uint4 v = rowp[i * 256 + tid];
        const int base = (i * 256 + tid) * 16;
        unsigned int w[4] = {v.x, v.y, v.z, v.w};
#pragma unroll
        for (int k = 0; k < 4; ++k) {
            if (!pre || (w[k] & 0x80808080u)) {
#pragma unroll
                for (int jj = 0; jj < 4; ++jj) {
                    unsigned int bb = (w[k] >> (8 * jj)) & 0xffu;
                    if (bb >= uH) {
                        int p = atomicAdd(&scal[1], 1);
                        if (p < 1024) cidx[p] = base + 4 * k + jj;
                    }
                }
            }
        }
    }
    __syncthreads();
    const int ncand = min(scal[1], 1024);

    // ---- exact fp32 rescore: 16-lane groups, 4 candidates per wave in flight ----
    const int gid = tid >> 4, gl = tid & 15;
    const float4* q4 = (const float4*)qs;
    for (int i = gid; i < ncand; i += 16) {
        const int idx = cidx[i];
        const float4* kp = (const float4*)(key + (size_t)idx * KDIM);
        float p = 0.f;
#pragma unroll
        for (int u = 0; u < 4; ++u) {
            float4 kk = kp[gl * 4 + u];
            float4 qq = q4[gl * 4 + u];
            p += kk.x * qq.x + kk.y * qq.y + kk.z * qq.z + kk.w * qq.w;
        }
#pragma unroll
        for (int off = 1; off < 16; off <<= 1) p += __shfl_xor(p, off, 64);
        if (gl == 0) {
            float e = expf(p - 1.0f);
            float h = hist[idx];
            csc[i] = e * (h + BETA);
            float j = e * (ALPHA * h + BETA);
            cjj[i] = j;
            cjv[i] = j * vals[idx];
        }
    }
    __syncthreads();

    // ---- exact top-128 among candidates (count-based; ties -> lower index) ----
    const int wave = tid >> 6, lane = tid & 63;
    float pn = 0.f, pd = 0.f;
    for (int i = tid; i < ncand; i += 256) {
        float si = csc[i]; int ii = cidx[i]; int rank = 0;
        for (int t = 0; t < ncand; ++t) {
            float st = csc[t];
            rank += (st > si || (st == si && cidx[t] < ii)) ? 1 : 0;
        }
        if (rank < CHOOSEK) { pn += cjv[i]; pd += cjj[i]; }
    }
#pragma unroll
    for (int off = 32; off > 0; off >>= 1) {
        pn += __shfl_xor(pn, off, 64);
        pd += __shfl_xor(pd, off, 64);
    }
    if (lane == 0) { wred[wave] = pn; wred[4 + wave] = pd; }
    __syncthreads();
    if (tid == 0) {
        float n = wred[0] + wred[1] + wred[2] + wred[3];
        float d = wred[4] + wred[5] + wred[6] + wred[7];
        out[b] = n / d;
    }
}

// -------------------------------------------------------------------------
extern "C" void kernel_launch(void* const* d_in, const int* in_sizes, int n_in,
                              void* d_out, int out_size, void* d_ws, size_t ws_size,
                              hipStream_t stream)
{
    (void)in_sizes; (void)n_in; (void)out_size; (void)ws_size;
    const float* q    = (const float*)d_in[0];
    const float* key  = (const float*)d_in[1];
    const float* hist = (const float*)d_in[2];
    const float* vals = (const float*)d_in[3];
    float* out = (float*)d_out;

    // workspace layout (96.5 MiB total):
    unsigned char*  s8 = (unsigned char*)d_ws;                                  // 64 MiB u8 keys
    unsigned short* kb = (unsigned short*)((char*)d_ws + ((size_t)64 << 20));   // 32 MiB bf16 key
    unsigned short* qb = (unsigned short*)((char*)d_ws + ((size_t)96 << 20));   // 512 KiB bf16 q

    convert_kernel<<<8320, 256, 0, stream>>>(q, key, qb, kb);
    score_kernel<<<4096, 256, 0, stream>>>(qb, kb, hist, s8);
    select_kernel<<<BATCH, 256, 0, stream>>>(q, key, hist, vals, s8, out);
}